// Round 13
// baseline (248.694 us; speedup 1.0000x reference)
//
#include <hip/hip_runtime.h>
#include <stdint.h>
#include <stddef.h>

typedef unsigned short u16;
typedef unsigned int u32;
typedef __bf16 bf16x8 __attribute__((ext_vector_type(8)));
typedef _Float16 f16x8 __attribute__((ext_vector_type(8)));
typedef float f32x4 __attribute__((ext_vector_type(4)));

#define TT 16384
#define NG 16
#define MAXT 272   // sum_g ceil(len_g/64) <= 256+16 = 272; 272 = 8*34
#define SCL 0.18033688011112042f   // log2(e)/sqrt(64)

static __device__ __forceinline__ unsigned f2bf_u(float f) {
  unsigned u = __float_as_uint(f);
  return (u + 0x7fffu + ((u >> 16) & 1u)) >> 16;   // RNE fp32->bf16
}

// async global->LDS, 16B per lane; LDS dst is wave-uniform base + lane*16
static __device__ __forceinline__ void gl_lds16(const u16* g, u16* l) {
  __builtin_amdgcn_global_load_lds(
      (const __attribute__((address_space(1))) u32*)g,
      (__attribute__((address_space(3))) u32*)l, 16, 0, 0);
}

// DPP cross-lane within 16-lane row (VALU pipe, no DS traffic)
template <int CTRL>
static __device__ __forceinline__ float dppf(float x) {
  return __int_as_float(__builtin_amdgcn_mov_dpp(__float_as_int(x), CTRL, 0xF, 0xF, true));
}
// xor1=0xB1, xor2=0x4E, ror4=0x124, ror8=0x128, half_mirror=0x141

// ---------------------------------------------------------------------------
// cast_kernel: pure cast, NO LDS -> 8 blocks/CU, all 1120 blocks co-resident.
// Round-13 (round-11 retry; round-12 compile fix): nontemporal loads need a
// clang ext_vector type, not HIP_vector_type float4 -> use f32x4. x/ipw are
// read-once fp32; NT keeps them from evicting xb/ipwb out of L2.
// ---------------------------------------------------------------------------
#define NXF4 2097152   // 16384*512/4
#define NWQ4 65536     // 512*512/4 (Wq rows of in_proj_w)

__global__ __launch_bounds__(256) void cast_kernel(
    const float* __restrict__ x, const float* __restrict__ ipw,
    u16* __restrict__ xb, u16* __restrict__ ipwb) {
  const int base = blockIdx.x * 2048 + threadIdx.x;
#pragma unroll
  for (int u = 0; u < 8; ++u) {
    int j = base + u * 256;
    f32x4 f;
    if (j < NXF4) f = __builtin_nontemporal_load(((const f32x4*)x) + j);
    else          f = __builtin_nontemporal_load(((const f32x4*)ipw) + (j - NXF4));
    if (j >= NXF4 && j < NXF4 + NWQ4) { f[0] *= SCL; f[1] *= SCL; f[2] *= SCL; f[3] *= SCL; }
    uint2 o;
    o.x = f2bf_u(f[0]) | (f2bf_u(f[1]) << 16);
    o.y = f2bf_u(f[2]) | (f2bf_u(f[3]) << 16);
    if (j < NXF4) ((uint2*)xb)[j] = o;
    else          ((uint2*)ipwb)[j - NXF4] = o;
  }
}

// ---------------------------------------------------------------------------
// wc_seg_kernel: 273 blocks, all co-resident (zero dispatch tail).
//  blocks 0..255  : Wc = Wl*Wo, K-split x4; sWlT transposed+padded staging.
//                   unroll 4->8 (8 Wo L2-latency loads in flight, halves the
//                   latency chain; isolated retest of round-6's confound).
//  blocks 256..271: bc = Wl*bo + bl, 8-lane DPP reduce.
//  block 272      : seg worklist + bqk bias scale.
// ---------------------------------------------------------------------------
__global__ __launch_bounds__(256) void wc_seg_kernel(
    const int* __restrict__ batch, const float* __restrict__ ipb,
    float* __restrict__ bqk, int* __restrict__ seg,
    const float* __restrict__ Wl, const float* __restrict__ Wo,
    const float* __restrict__ bo, const float* __restrict__ bl,
    u16* __restrict__ Wc, float* __restrict__ bc) {
  const int tid = threadIdx.x;
  const int bxx = blockIdx.x;
  __shared__ float sWlT[512 * 20];   // [k][r], padded 16->20 for b128 align
  __shared__ float red2[4096];       // [ks][16][64]
  __shared__ int scnt[NG];
  if (bxx < 256) {                   // ---- wc part ----
    const int r0 = (bxx >> 3) << 4;  // 32 row-groups of 16
    const int c0 = (bxx & 7) << 6;   // 8 col-groups of 64
    for (int i = tid; i < 16 * 512; i += 256) {
      int r = i >> 9, k = i & 511;
      sWlT[k * 20 + r] = Wl[(r0 + r) * 512 + k];
    }
    __syncthreads();
    const int c = c0 + (tid & 63), ks = tid >> 6;
    float a[16];
#pragma unroll
    for (int r = 0; r < 16; ++r) a[r] = 0.f;
    const int kbeg = ks << 7;
#pragma unroll 8
    for (int kk = 0; kk < 128; ++kk) {
      int k = kbeg + kk;
      float w = Wo[k * 512 + c];
      const f32x4* sp = (const f32x4*)(sWlT + k * 20);
#pragma unroll
      for (int rq = 0; rq < 4; ++rq) {
        f32x4 v = sp[rq];
        a[rq * 4 + 0] += v[0] * w; a[rq * 4 + 1] += v[1] * w;
        a[rq * 4 + 2] += v[2] * w; a[rq * 4 + 3] += v[3] * w;
      }
    }
#pragma unroll
    for (int r = 0; r < 16; ++r) red2[(ks << 10) + (r << 6) + (tid & 63)] = a[r];
    __syncthreads();
#pragma unroll
    for (int q = 0; q < 4; ++q) {
      int oi = (q << 8) + tid;       // 0..1023 -> (r, cc)
      int r = oi >> 6, cc = oi & 63;
      float v = (red2[(r << 6) + cc] + red2[1024 + (r << 6) + cc]) +
                (red2[2048 + (r << 6) + cc] + red2[3072 + (r << 6) + cc]);
      Wc[(size_t)(r0 + r) * 512 + c0 + cc] = (u16)f2bf_u(v);
    }
    return;
  }
  if (bxx < 272) {                   // ---- bc part: 32 rows/block ----
    const int row = ((bxx - 256) << 5) + (tid >> 3), s = tid & 7;
    float acc = 0.f;
#pragma unroll 8
    for (int j = 0; j < 64; ++j)
      acc += Wl[(size_t)row * 512 + (j << 3) + s] * bo[(j << 3) + s];
    acc += dppf<0xB1>(acc);          // xor1
    acc += dppf<0x4E>(acc);          // xor2
    acc += dppf<0x141>(acc);         // row_half_mirror
    if (s == 0) bc[row] = acc + bl[row];
    return;
  }
  // ---- seg part (bxx == 272) ----
  if (tid < NG) scnt[tid] = 0;
  __syncthreads();
  for (int i = tid; i < TT; i += 256) atomicAdd(&scnt[batch[i] & (NG - 1)], 1);
  for (int i = tid; i < 1024; i += 256) bqk[i] = ipb[i] * (i < 512 ? SCL : 1.f);
  __syncthreads();
  if (tid == 0) {
    int off = 0, nt = 0;
    for (int g = 0; g < NG; ++g) { seg[1 + g] = off; off += scnt[g]; }
    seg[1 + NG] = off;
    for (int g = 0; g < NG; ++g)
      for (int q0 = 0; q0 < scnt[g]; q0 += 64) { seg[32 + nt] = g; seg[320 + nt] = q0; ++nt; }
    seg[0] = nt;
  }
}

// ---------------------------------------------------------------------------
// gemm_core: C = A[M,K] * Bt[N,K]^T + bias   (bf16 MFMA 16x16x32)
// 128x128 tile, BK=64, 4 waves, 4x4 acc frags; swizzled LDS; gl_lds16 staging.
// EPI 0: f32 row-major, bias[col]          (final output)
// EPI 1: col<512 -> q row-major bf16; col>=512 -> K packed tiles (bf16)
//        kpk[h][t/64][t&63][d]
// EPI 2: V packed tiles in F16, bias[row]
//        vpk[h][t/64][d][t&63]
// ---------------------------------------------------------------------------
template <int EPI>
static __device__ __forceinline__ void gemm_core(
    u16* As, u16* Bs, int bidx,
    const u16* __restrict__ A, const u16* __restrict__ Bt, void* __restrict__ C,
    void* __restrict__ C2, const float* __restrict__ bias, int M, int N, int K) {
  const int nn = N >> 7;
  const int bm = bidx / nn, bn = bidx % nn;
  const int tid = threadIdx.x;
  const int w = tid >> 6, lane = tid & 63;
  const int quad = lane >> 4, l16 = lane & 15;
  const int wm = w >> 1, wn = w & 1;
  f32x4 acc[4][4];
#pragma unroll
  for (int mi = 0; mi < 4; ++mi)
#pragma unroll
    for (int ni = 0; ni < 4; ++ni) acc[mi][ni] = (f32x4){0.f, 0.f, 0.f, 0.f};
  const int sr = lane >> 3, scn = lane & 7;
  const int rowA0 = bm << 7, rowB0 = bn << 7;
  for (int kt = 0; kt < K; kt += 64) {
#pragma unroll
    for (int u = 0; u < 4; ++u) {
      int rbase = (w << 5) + (u << 3);
      int ml = rbase + sr;
      int ca = scn ^ (ml & 7);
      gl_lds16(A  + (size_t)(rowA0 + ml) * K + kt + ca * 8, As + (rbase << 6));
      gl_lds16(Bt + (size_t)(rowB0 + ml) * K + kt + ca * 8, Bs + (rbase << 6));
    }
    __syncthreads();
#pragma unroll
    for (int ks = 0; ks < 2; ++ks) {
      bf16x8 af[4], bfv[4];
#pragma unroll
      for (int mi = 0; mi < 4; ++mi) {
        int r = (wm << 6) + (mi << 4) + l16;
        af[mi] = *(const bf16x8*)(As + (r << 6) + ((((ks << 2) + quad) ^ (r & 7)) << 3));
      }
#pragma unroll
      for (int ni = 0; ni < 4; ++ni) {
        int r = (wn << 6) + (ni << 4) + l16;
        bfv[ni] = *(const bf16x8*)(Bs + (r << 6) + ((((ks << 2) + quad) ^ (r & 7)) << 3));
      }
#pragma unroll
      for (int mi = 0; mi < 4; ++mi)
#pragma unroll
        for (int ni = 0; ni < 4; ++ni)
          acc[mi][ni] = __builtin_amdgcn_mfma_f32_16x16x32_bf16(af[mi], bfv[ni], acc[mi][ni], 0, 0, 0);
    }
    __syncthreads();
  }
#pragma unroll
  for (int mi = 0; mi < 4; ++mi) {
#pragma unroll
    for (int ni = 0; ni < 4; ++ni) {
      int row = rowA0 + (wm << 6) + (mi << 4) + (quad << 2);
      int col = rowB0 + (wn << 6) + (ni << 4) + l16;
      float bvc = (EPI == 2) ? 0.f : bias[col];
#pragma unroll
      for (int r = 0; r < 4; ++r) {
        float v = acc[mi][ni][r] + ((EPI == 2) ? bias[row + r] : bvc);
        if (EPI == 0) {
          ((float*)C)[(size_t)(row + r) * N + col] = v;
        } else if (EPI == 1) {
          if (col < 512) {
            ((u16*)C)[(size_t)(row + r) * 512 + col] = (u16)f2bf_u(v);
          } else {
            int f = col - 512, hh = f >> 6, d = f & 63, t = row + r;
            ((u16*)C2)[(size_t)hh * (TT * 64) + ((t >> 6) << 12) + ((t & 63) << 6) + d] = (u16)f2bf_u(v);
          }
        } else {
          int f = row + r, hh = f >> 6, d = f & 63, t = col;
          ((u16*)C)[(size_t)hh * (TT * 64) + ((t >> 6) << 12) + (d << 6) + (t & 63)] =
              __builtin_bit_cast(unsigned short, (_Float16)v);
        }
      }
    }
  }
}

// fused projection GEMMs: blocks 0..1023 -> QK (EPI1); 1024..1535 -> V (EPI2)
__global__ __launch_bounds__(256) void gemm_qkv(
    const u16* __restrict__ xb, const u16* __restrict__ ipwb,
    u16* __restrict__ qb, u16* __restrict__ kpk, u16* __restrict__ vpk,
    const float* __restrict__ bqk, const float* __restrict__ ipb) {
  __shared__ __align__(16) u16 As[128 * 64];
  __shared__ __align__(16) u16 Bs[128 * 64];
  if (blockIdx.x < 1024)
    gemm_core<1>(As, Bs, blockIdx.x, xb, ipwb, qb, kpk, bqk, TT, 1024, 512);
  else
    gemm_core<2>(As, Bs, blockIdx.x - 1024, ipwb + 1024 * 512, xb, vpk, nullptr,
                 ipb + 1024, 512, TT, 512);
}

__global__ __launch_bounds__(256) void gemm_out(
    const u16* __restrict__ ctxb, const u16* __restrict__ wcb,
    float* __restrict__ out, const float* __restrict__ bc) {
  __shared__ __align__(16) u16 As[128 * 64];
  __shared__ __align__(16) u16 Bs[128 * 64];
  gemm_core<0>(As, Bs, blockIdx.x, ctxb, wcb, out, nullptr, bc, TT, 512, 512);
}

// ---------------------------------------------------------------------------
// attn v13 (round-9 VERIFIED): in-register softmax via swapped QK^T +
// permlane A-frag assembly (natural key order, V read conflict-free),
// XCD tile swizzle, (256,5), LDS 32KB.
// Round-9 counters: 64.2us, VGPR 44, conflicts 0, FETCH 32MB, absmax 6.1e-5.
// ---------------------------------------------------------------------------
__global__ __launch_bounds__(256, 5) void attn_kernel(
    const u16* __restrict__ qb, const u16* __restrict__ kpk,
    const u16* __restrict__ vpk, u16* __restrict__ ctx, const int* __restrict__ seg) {
  const int bxr = blockIdx.x;
  const int bx = ((bxr & 7) * 34) + (bxr >> 3);   // XCD-contiguous tiles
  if (bx >= seg[0]) return;
  const int h = blockIdx.y;
  const int g = seg[32 + bx], q0 = seg[320 + bx];
  const int s0 = seg[1 + g], len = seg[2 + g] - s0;
  const int tid = threadIdx.x, w = tid >> 6, lane = tid & 63;
  const int quad = lane >> 4, l16 = lane & 15;

  __shared__ __align__(16) u16 Ks[2][4096];
  __shared__ __align__(16) u16 Vs[2][4096];

  const u16* kh = kpk + (size_t)h * (TT * 64);
  const u16* vh = vpk + (size_t)h * (TT * 64);

  // Q fragments, 16 rows/wave, zero beyond len (used as B-operand now)
  bf16x8 afq[2];
#pragma unroll
  for (int ks = 0; ks < 2; ++ks) {
    int ql = (w << 4) + l16;
    uint4 tmp = {0u, 0u, 0u, 0u};
    if (q0 + ql < len)
      tmp = *(const uint4*)(qb + (size_t)(s0 + q0 + ql) * 512 + (h << 6) + (((ks << 2) + quad) << 3));
    afq[ks] = __builtin_bit_cast(bf16x8, tmp);
  }

  float lacc = 0.f;
  f32x4 O[4];
#pragma unroll
  for (int dt = 0; dt < 4; ++dt) O[dt] = (f32x4){0.f, 0.f, 0.f, 0.f};

  const int delta = s0 & 7;               // alignment shift of kv window
  const int srl = lane >> 3, sc = lane & 7;
  int vcl = ((len - 8 + delta) & ~7) - delta;   // safe aligned start, +8 <= len
  if (vcl < -delta) vcl = -delta;

  // per-lane incremental staging offsets (u16 units), window at kv0=-delta
  const int rb0 = (w << 4), rb1 = rb0 + 8;
  const int r0 = rb0 + srl, r1 = rb1 + srl;
  const int ca0 = sc ^ (r0 & 7), ca1 = sc ^ (r1 & 7);
  const int t0 = s0 - delta;
  int tk = t0 + r0;
  u32 kOffA = ((tk >> 6) << 12) + ((tk & 63) << 6) + (ca0 << 3);
  tk = t0 + r1;
  u32 kOffB = ((tk >> 6) << 12) + ((tk & 63) << 6) + (ca1 << 3);
  int tv = t0 + (ca0 << 3);
  u32 vOffA = ((tv >> 6) << 12) + (r0 << 6) + (tv & 63);
  tv = t0 + (ca1 << 3);
  u32 vOffB = ((tv >> 6) << 12) + (r1 << 6) + (tv & 63);

  auto stage = [&](int kv0, u16* bk, u16* bvs) {
    if (kv0 + 64 <= len) {                 // interior: pure pointer advance
      gl_lds16(kh + kOffA, bk + (rb0 << 6));
      gl_lds16(kh + kOffB, bk + (rb1 << 6));
      gl_lds16(vh + vOffA, bvs + (rb0 << 6));
      gl_lds16(vh + vOffB, bvs + (rb1 << 6));
    } else {                               // final window: clamped addressing
      int tr = kv0 + r0; tr = tr < len - 1 ? tr : len - 1; int tc = s0 + tr;
      gl_lds16(kh + ((tc >> 6) << 12) + ((tc & 63) << 6) + (ca0 << 3), bk + (rb0 << 6));
      tr = kv0 + r1; tr = tr < len - 1 ? tr : len - 1; tc = s0 + tr;
      gl_lds16(kh + ((tc >> 6) << 12) + ((tc & 63) << 6) + (ca1 << 3), bk + (rb1 << 6));
      int st = kv0 + (ca0 << 3); st = st < len ? st : vcl; tc = s0 + st;
      gl_lds16(vh + ((tc >> 6) << 12) + (r0 << 6) + (tc & 63), bvs + (rb0 << 6));
      st = kv0 + (ca1 << 3); st = st < len ? st : vcl; tc = s0 + st;
      gl_lds16(vh + ((tc >> 6) << 12) + (r1 << 6) + (tc & 63), bvs + (rb1 << 6));
    }
    kOffA += 4096; kOffB += 4096; vOffA += 4096; vOffB += 4096;
  };

  const int nIt = (len + delta + 63) >> 6;

  auto body = [&](int kv0, int i, const u16* Kc, const u16* Vc, u16* Kn, u16* Vn) {
    __syncthreads();                        // cur buffers landed; prev reads done
    if (i + 1 < nIt) stage(kv0 + 64, Kn, Vn);

    // S^T = K Q^T (pre-scaled, log2 domain): lane holds S[key][q=l16]
    f32x4 s[4];
#pragma unroll
    for (int nt = 0; nt < 4; ++nt) s[nt] = (f32x4){0.f, 0.f, 0.f, 0.f};
    __builtin_amdgcn_s_setprio(1);
#pragma unroll
    for (int ks = 0; ks < 2; ++ks) {
#pragma unroll
      for (int nt = 0; nt < 4; ++nt) {
        int kr = (nt << 4) + l16;
        bf16x8 bk = *(const bf16x8*)(Kc + (kr << 6) + ((((ks << 2) + quad) ^ (kr & 7)) << 3));
        s[nt] = __builtin_amdgcn_mfma_f32_16x16x32_bf16(bk, afq[ks], s[nt], 0, 0, 0);
      }
    }
    __builtin_amdgcn_s_setprio(0);
    // key mask only on edge windows (wave-uniform branch); key = quad*4+r now
    if ((kv0 < 0) | (kv0 + 64 > len)) {
#pragma unroll
      for (int nt = 0; nt < 4; ++nt)
#pragma unroll
        for (int r = 0; r < 4; ++r) {
          int ki = kv0 + (nt << 4) + (quad << 2) + r;
          s[nt][r] += ((unsigned)ki < (unsigned)len) ? 0.f : -1e30f;
        }
    }
    // exp2 + scalar l partial (all 16 values belong to q=l16)
#pragma unroll
    for (int nt = 0; nt < 4; ++nt)
#pragma unroll
      for (int r = 0; r < 4; ++r) s[nt][r] = __builtin_amdgcn_exp2f(s[nt][r]);
#pragma unroll
    for (int nt = 0; nt < 4; ++nt)
      lacc += (s[nt][0] + s[nt][1]) + (s[nt][2] + s[nt][3]);

    // P -> f16 pairs in-register
    u32 pr[8];
#pragma unroll
    for (int nt = 0; nt < 4; ++nt) {
      pr[nt * 2 + 0] = __builtin_bit_cast(u32, __builtin_amdgcn_cvt_pkrtz(s[nt][0], s[nt][1]));
      pr[nt * 2 + 1] = __builtin_bit_cast(u32, __builtin_amdgcn_cvt_pkrtz(s[nt][2], s[nt][3]));
    }
    // PV: assemble A-frags with keys in NATURAL 8*quad+j order:
    // apv[c]@q = pr[2(q>>1)+(c&1)] @ quad 2(q&1)+(c>>1)
    //          = swap32+swap16 of (A,C) and (B,D). V read stays chunk=quad.
#pragma unroll
    for (int ks = 0; ks < 2; ++ks) {
      u32 A = pr[4 * ks + 0], B = pr[4 * ks + 1];
      u32 C = pr[4 * ks + 2], D = pr[4 * ks + 3];
      asm("v_permlane32_swap_b32 %0, %1" : "+v"(A), "+v"(C));
      asm("v_permlane16_swap_b32 %0, %1" : "+v"(A), "+v"(C));
      asm("v_permlane32_swap_b32 %0, %1" : "+v"(B), "+v"(D));
      asm("v_permlane16_swap_b32 %0, %1" : "+v"(B), "+v"(D));
      uint4 apv = {A, B, C, D};
      f16x8 ap = __builtin_bit_cast(f16x8, apv);
      __builtin_amdgcn_s_setprio(1);
#pragma unroll
      for (int dt = 0; dt < 4; ++dt) {
        int vr = (dt << 4) + l16;
        f16x8 bv = *(const f16x8*)(Vc + (vr << 6) + ((((ks << 2) + quad) ^ (vr & 7)) << 3));
        O[dt] = __builtin_amdgcn_mfma_f32_16x16x32_f16(ap, bv, O[dt], 0, 0, 0);
      }
      __builtin_amdgcn_s_setprio(0);
    }
  };

  stage(-delta, Ks[0], Vs[0]);
  {
    int kv0 = -delta, i = 0;
    while (i < nIt) {
      body(kv0, i, Ks[0], Vs[0], Ks[1], Vs[1]);
      ++i; kv0 += 64;
      if (i >= nIt) break;
      body(kv0, i, Ks[1], Vs[1], Ks[0], Vs[0]);
      ++i; kv0 += 64;
    }
  }

  // fold l across the 4 quads (each lane holds partial for q=l16)
  {
    u32 a = __float_as_uint(lacc), b = a;
    asm("v_permlane32_swap_b32 %0, %1" : "+v"(a), "+v"(b));
    float t = __uint_as_float(a) + __uint_as_float(b);
    a = __float_as_uint(t); b = a;
    asm("v_permlane16_swap_b32 %0, %1" : "+v"(a), "+v"(b));
    lacc = __uint_as_float(a) + __uint_as_float(b);
  }
  // inv per (quad, r): O rows are q = quad*4+r; L lives at lane l16=q
  {
    f32x4 inv;
#pragma unroll
    for (int r = 0; r < 4; ++r) {
      float Lr = __int_as_float(
          __builtin_amdgcn_ds_bpermute((((quad << 2) + r) << 2), __float_as_int(lacc)));
      inv[r] = 1.f / Lr;
    }
#pragma unroll
    for (int dt = 0; dt < 4; ++dt)
#pragma unroll
      for (int r = 0; r < 4; ++r) {
        int ql = (w << 4) + (quad << 2) + r;
        if (q0 + ql < len)
          ctx[(size_t)(s0 + q0 + ql) * 512 + (h << 6) + (dt << 4) + l16] = (u16)f2bf_u(O[dt][r] * inv[r]);
      }
  }
}

// ---------------------------------------------------------------------------
extern "C" void kernel_launch(void* const* d_in, const int* in_sizes, int n_in,
                              void* d_out, int out_size, void* d_ws, size_t ws_size,
                              hipStream_t stream) {
  const float* x = (const float*)d_in[0];
  const int* batch = (const int*)d_in[1];   // harness passes integers as int32
  const float* ipw = (const float*)d_in[2];
  const float* ipb = (const float*)d_in[3];
  const float* opw = (const float*)d_in[4];
  const float* opb = (const float*)d_in[5];
  const float* lw = (const float*)d_in[6];
  const float* lb = (const float*)d_in[7];
  float* out = (float*)d_out;
  char* ws = (char*)d_ws;

  u16* xb   = (u16*)(ws + 0);              // 16 MB (x bf16)
  u16* ctxb = (u16*)(ws + 0);              // aliases xb (disjoint liveness)
  u16* qb   = (u16*)(ws + 16777216);       // 16 MB: [T][512] q (pre-scaled)
  u16* kpk  = (u16*)(ws + 33554432);       // 16 MB: packed K tiles (bf16)
  u16* vpk  = (u16*)(ws + 50331648);       // 16 MB: packed V tiles (f16)
  u16* ipwb = (u16*)(ws + 67108864);       // 1.5 MB
  u16* wcb  = (u16*)(ws + 68681728);       // 0.5 MB
  float* bc = (float*)(ws + 69206016);     // 2 KB
  float* bqk= (float*)(ws + 69208064);     // 4 KB
  int* seg  = (int*)(ws + 69212160);       // 4 KB

  cast_kernel<<<1120, 256, 0, stream>>>(x, ipw, xb, ipwb);
  wc_seg_kernel<<<273, 256, 0, stream>>>(batch, ipb, bqk, seg, lw, opw, opb, lb,
                                         wcb, bc);
  gemm_qkv<<<1536, 256, 0, stream>>>(xb, ipwb, qb, kpk, vpk, bqk, ipb);
  attn_kernel<<<dim3(MAXT, 8), 256, 0, stream>>>(qb, kpk, vpk, ctxb, seg);
  gemm_out<<<512, 256, 0, stream>>>(ctxb, wcb, out, bc);
  (void)in_sizes; (void)n_in; (void)out_size; (void)ws_size;
}

// Round 14
// 240.784 us; speedup vs baseline: 1.0329x; 1.0329x over previous
//
#include <hip/hip_runtime.h>
#include <stdint.h>
#include <stddef.h>

typedef unsigned short u16;
typedef unsigned int u32;
typedef __bf16 bf16x8 __attribute__((ext_vector_type(8)));
typedef _Float16 f16x8 __attribute__((ext_vector_type(8)));
typedef float f32x4 __attribute__((ext_vector_type(4)));

#define TT 16384
#define NG 16
#define MAXT 272   // sum_g ceil(len_g/64) <= 256+16 = 272; 272 = 8*34
#define SCL 0.18033688011112042f   // log2(e)/sqrt(64)

static __device__ __forceinline__ unsigned f2bf_u(float f) {
  unsigned u = __float_as_uint(f);
  return (u + 0x7fffu + ((u >> 16) & 1u)) >> 16;   // RNE fp32->bf16
}

// async global->LDS, 16B per lane; LDS dst is wave-uniform base + lane*16
static __device__ __forceinline__ void gl_lds16(const u16* g, u16* l) {
  __builtin_amdgcn_global_load_lds(
      (const __attribute__((address_space(1))) u32*)g,
      (__attribute__((address_space(3))) u32*)l, 16, 0, 0);
}

// DPP cross-lane within 16-lane row (VALU pipe, no DS traffic)
template <int CTRL>
static __device__ __forceinline__ float dppf(float x) {
  return __int_as_float(__builtin_amdgcn_mov_dpp(__float_as_int(x), CTRL, 0xF, 0xF, true));
}
// xor1=0xB1, xor2=0x4E, ror4=0x124, ror8=0x128, half_mirror=0x141

// ---------------------------------------------------------------------------
// cast_kernel: pure cast, NO LDS -> 8 blocks/CU, all 1120 blocks co-resident.
// (round-9 verified form; round-13's NT-load variant measured negative)
// ---------------------------------------------------------------------------
#define NXF4 2097152   // 16384*512/4
#define NWQ4 65536     // 512*512/4 (Wq rows of in_proj_w)

__global__ __launch_bounds__(256) void cast_kernel(
    const float* __restrict__ x, const float* __restrict__ ipw,
    u16* __restrict__ xb, u16* __restrict__ ipwb) {
  const int base = blockIdx.x * 2048 + threadIdx.x;
#pragma unroll
  for (int u = 0; u < 8; ++u) {
    int j = base + u * 256;
    float4 f;
    if (j < NXF4) f = ((const float4*)x)[j];
    else          f = ((const float4*)ipw)[j - NXF4];
    if (j >= NXF4 && j < NXF4 + NWQ4) { f.x *= SCL; f.y *= SCL; f.z *= SCL; f.w *= SCL; }
    uint2 o;
    o.x = f2bf_u(f.x) | (f2bf_u(f.y) << 16);
    o.y = f2bf_u(f.z) | (f2bf_u(f.w) << 16);
    if (j < NXF4) ((uint2*)xb)[j] = o;
    else          ((uint2*)ipwb)[j - NXF4] = o;
  }
}

// ---------------------------------------------------------------------------
// wc_seg_kernel: 273 blocks, all co-resident (zero dispatch tail).
// (round-9 verified form; round-13's unroll-8 measured negative)
//  blocks 0..255  : Wc = Wl*Wo, K-split x4; sWlT transposed+padded staging.
//  blocks 256..271: bc = Wl*bo + bl, 8-lane DPP reduce.
//  block 272      : seg worklist + bqk bias scale.
// ---------------------------------------------------------------------------
__global__ __launch_bounds__(256) void wc_seg_kernel(
    const int* __restrict__ batch, const float* __restrict__ ipb,
    float* __restrict__ bqk, int* __restrict__ seg,
    const float* __restrict__ Wl, const float* __restrict__ Wo,
    const float* __restrict__ bo, const float* __restrict__ bl,
    u16* __restrict__ Wc, float* __restrict__ bc) {
  const int tid = threadIdx.x;
  const int bxx = blockIdx.x;
  __shared__ float sWlT[512 * 20];   // [k][r], padded 16->20 for b128 align
  __shared__ float red2[4096];       // [ks][16][64]
  __shared__ int scnt[NG];
  if (bxx < 256) {                   // ---- wc part ----
    const int r0 = (bxx >> 3) << 4;  // 32 row-groups of 16
    const int c0 = (bxx & 7) << 6;   // 8 col-groups of 64
    for (int i = tid; i < 16 * 512; i += 256) {
      int r = i >> 9, k = i & 511;
      sWlT[k * 20 + r] = Wl[(r0 + r) * 512 + k];
    }
    __syncthreads();
    const int c = c0 + (tid & 63), ks = tid >> 6;
    float a[16];
#pragma unroll
    for (int r = 0; r < 16; ++r) a[r] = 0.f;
    const int kbeg = ks << 7;
#pragma unroll 4
    for (int kk = 0; kk < 128; ++kk) {
      int k = kbeg + kk;
      float w = Wo[k * 512 + c];
      const f32x4* sp = (const f32x4*)(sWlT + k * 20);
#pragma unroll
      for (int rq = 0; rq < 4; ++rq) {
        f32x4 v = sp[rq];
        a[rq * 4 + 0] += v[0] * w; a[rq * 4 + 1] += v[1] * w;
        a[rq * 4 + 2] += v[2] * w; a[rq * 4 + 3] += v[3] * w;
      }
    }
#pragma unroll
    for (int r = 0; r < 16; ++r) red2[(ks << 10) + (r << 6) + (tid & 63)] = a[r];
    __syncthreads();
#pragma unroll
    for (int q = 0; q < 4; ++q) {
      int oi = (q << 8) + tid;       // 0..1023 -> (r, cc)
      int r = oi >> 6, cc = oi & 63;
      float v = (red2[(r << 6) + cc] + red2[1024 + (r << 6) + cc]) +
                (red2[2048 + (r << 6) + cc] + red2[3072 + (r << 6) + cc]);
      Wc[(size_t)(r0 + r) * 512 + c0 + cc] = (u16)f2bf_u(v);
    }
    return;
  }
  if (bxx < 272) {                   // ---- bc part: 32 rows/block ----
    const int row = ((bxx - 256) << 5) + (tid >> 3), s = tid & 7;
    float acc = 0.f;
#pragma unroll 8
    for (int j = 0; j < 64; ++j)
      acc += Wl[(size_t)row * 512 + (j << 3) + s] * bo[(j << 3) + s];
    acc += dppf<0xB1>(acc);          // xor1
    acc += dppf<0x4E>(acc);          // xor2
    acc += dppf<0x141>(acc);         // row_half_mirror
    if (s == 0) bc[row] = acc + bl[row];
    return;
  }
  // ---- seg part (bxx == 272) ----
  if (tid < NG) scnt[tid] = 0;
  __syncthreads();
  for (int i = tid; i < TT; i += 256) atomicAdd(&scnt[batch[i] & (NG - 1)], 1);
  for (int i = tid; i < 1024; i += 256) bqk[i] = ipb[i] * (i < 512 ? SCL : 1.f);
  __syncthreads();
  if (tid == 0) {
    int off = 0, nt = 0;
    for (int g = 0; g < NG; ++g) { seg[1 + g] = off; off += scnt[g]; }
    seg[1 + NG] = off;
    for (int g = 0; g < NG; ++g)
      for (int q0 = 0; q0 < scnt[g]; q0 += 64) { seg[32 + nt] = g; seg[320 + nt] = q0; ++nt; }
    seg[0] = nt;
  }
}

// ---------------------------------------------------------------------------
// gemm_core: C = A[M,K] * Bt[N,K]^T + bias   (bf16 MFMA 16x16x32)
// 128x128 tile, BK=64, 4 waves, 4x4 acc frags; swizzled LDS; gl_lds16 staging.
// EPI 0: f32 row-major, bias[col]          (final output)
// EPI 1: col<512 -> q row-major bf16; col>=512 -> K packed tiles (bf16)
//        kpk[h][t/64][t&63][d]
// EPI 2: V packed tiles in F16, bias[row]
//        vpk[h][t/64][d][t&63]
// ---------------------------------------------------------------------------
template <int EPI>
static __device__ __forceinline__ void gemm_core(
    u16* As, u16* Bs, int bidx,
    const u16* __restrict__ A, const u16* __restrict__ Bt, void* __restrict__ C,
    void* __restrict__ C2, const float* __restrict__ bias, int M, int N, int K) {
  const int nn = N >> 7;
  const int bm = bidx / nn, bn = bidx % nn;
  const int tid = threadIdx.x;
  const int w = tid >> 6, lane = tid & 63;
  const int quad = lane >> 4, l16 = lane & 15;
  const int wm = w >> 1, wn = w & 1;
  f32x4 acc[4][4];
#pragma unroll
  for (int mi = 0; mi < 4; ++mi)
#pragma unroll
    for (int ni = 0; ni < 4; ++ni) acc[mi][ni] = (f32x4){0.f, 0.f, 0.f, 0.f};
  const int sr = lane >> 3, scn = lane & 7;
  const int rowA0 = bm << 7, rowB0 = bn << 7;
  for (int kt = 0; kt < K; kt += 64) {
#pragma unroll
    for (int u = 0; u < 4; ++u) {
      int rbase = (w << 5) + (u << 3);
      int ml = rbase + sr;
      int ca = scn ^ (ml & 7);
      gl_lds16(A  + (size_t)(rowA0 + ml) * K + kt + ca * 8, As + (rbase << 6));
      gl_lds16(Bt + (size_t)(rowB0 + ml) * K + kt + ca * 8, Bs + (rbase << 6));
    }
    __syncthreads();
#pragma unroll
    for (int ks = 0; ks < 2; ++ks) {
      bf16x8 af[4], bfv[4];
#pragma unroll
      for (int mi = 0; mi < 4; ++mi) {
        int r = (wm << 6) + (mi << 4) + l16;
        af[mi] = *(const bf16x8*)(As + (r << 6) + ((((ks << 2) + quad) ^ (r & 7)) << 3));
      }
#pragma unroll
      for (int ni = 0; ni < 4; ++ni) {
        int r = (wn << 6) + (ni << 4) + l16;
        bfv[ni] = *(const bf16x8*)(Bs + (r << 6) + ((((ks << 2) + quad) ^ (r & 7)) << 3));
      }
#pragma unroll
      for (int mi = 0; mi < 4; ++mi)
#pragma unroll
        for (int ni = 0; ni < 4; ++ni)
          acc[mi][ni] = __builtin_amdgcn_mfma_f32_16x16x32_bf16(af[mi], bfv[ni], acc[mi][ni], 0, 0, 0);
    }
    __syncthreads();
  }
#pragma unroll
  for (int mi = 0; mi < 4; ++mi) {
#pragma unroll
    for (int ni = 0; ni < 4; ++ni) {
      int row = rowA0 + (wm << 6) + (mi << 4) + (quad << 2);
      int col = rowB0 + (wn << 6) + (ni << 4) + l16;
      float bvc = (EPI == 2) ? 0.f : bias[col];
#pragma unroll
      for (int r = 0; r < 4; ++r) {
        float v = acc[mi][ni][r] + ((EPI == 2) ? bias[row + r] : bvc);
        if (EPI == 0) {
          ((float*)C)[(size_t)(row + r) * N + col] = v;
        } else if (EPI == 1) {
          if (col < 512) {
            ((u16*)C)[(size_t)(row + r) * 512 + col] = (u16)f2bf_u(v);
          } else {
            int f = col - 512, hh = f >> 6, d = f & 63, t = row + r;
            ((u16*)C2)[(size_t)hh * (TT * 64) + ((t >> 6) << 12) + ((t & 63) << 6) + d] = (u16)f2bf_u(v);
          }
        } else {
          int f = row + r, hh = f >> 6, d = f & 63, t = col;
          ((u16*)C)[(size_t)hh * (TT * 64) + ((t >> 6) << 12) + (d << 6) + (t & 63)] =
              __builtin_bit_cast(unsigned short, (_Float16)v);
        }
      }
    }
  }
}

// fused projection GEMMs: blocks 0..1023 -> QK (EPI1); 1024..1535 -> V (EPI2)
__global__ __launch_bounds__(256) void gemm_qkv(
    const u16* __restrict__ xb, const u16* __restrict__ ipwb,
    u16* __restrict__ qb, u16* __restrict__ kpk, u16* __restrict__ vpk,
    const float* __restrict__ bqk, const float* __restrict__ ipb) {
  __shared__ __align__(16) u16 As[128 * 64];
  __shared__ __align__(16) u16 Bs[128 * 64];
  if (blockIdx.x < 1024)
    gemm_core<1>(As, Bs, blockIdx.x, xb, ipwb, qb, kpk, bqk, TT, 1024, 512);
  else
    gemm_core<2>(As, Bs, blockIdx.x - 1024, ipwb + 1024 * 512, xb, vpk, nullptr,
                 ipb + 1024, 512, TT, 512);
}

__global__ __launch_bounds__(256) void gemm_out(
    const u16* __restrict__ ctxb, const u16* __restrict__ wcb,
    float* __restrict__ out, const float* __restrict__ bc) {
  __shared__ __align__(16) u16 As[128 * 64];
  __shared__ __align__(16) u16 Bs[128 * 64];
  gemm_core<0>(As, Bs, blockIdx.x, ctxb, wcb, out, nullptr, bc, TT, 512, 512);
}

// ---------------------------------------------------------------------------
// attn v15: round-13 confirmed v13's pace-setter is the VALU chain (VALU 47%,
// MFMA 24%). The l-sum (16 VALU adds/iter) is matmul-shaped: l = P * ones.
// Move it to the idle matrix pipe: one extra mfma(ap, ones_f16, Ol) per ks
// (2 MFMA/iter) replaces all 16 adds AND deletes the end fold+ds_bpermute —
// every Ol column holds l[q=quad*4+r], so inv[r] = 1/Ol[r] is lane-local.
// Denominator now sums f16-rounded P, consistent with the f16 numerator.
// Rest identical to v13 (round-9 verified: conflicts 0, FETCH 32MB).
// Tripwires: absmax blowup => ones-operand layout wrong (revert);
// WRITE >20MB => spill from +8 VGPR; dur flat+VALU down => latency floor.
// ---------------------------------------------------------------------------
__global__ __launch_bounds__(256, 5) void attn_kernel(
    const u16* __restrict__ qb, const u16* __restrict__ kpk,
    const u16* __restrict__ vpk, u16* __restrict__ ctx, const int* __restrict__ seg) {
  const int bxr = blockIdx.x;
  const int bx = ((bxr & 7) * 34) + (bxr >> 3);   // XCD-contiguous tiles
  if (bx >= seg[0]) return;
  const int h = blockIdx.y;
  const int g = seg[32 + bx], q0 = seg[320 + bx];
  const int s0 = seg[1 + g], len = seg[2 + g] - s0;
  const int tid = threadIdx.x, w = tid >> 6, lane = tid & 63;
  const int quad = lane >> 4, l16 = lane & 15;

  __shared__ __align__(16) u16 Ks[2][4096];
  __shared__ __align__(16) u16 Vs[2][4096];

  const u16* kh = kpk + (size_t)h * (TT * 64);
  const u16* vh = vpk + (size_t)h * (TT * 64);

  // Q fragments, 16 rows/wave, zero beyond len (used as B-operand now)
  bf16x8 afq[2];
#pragma unroll
  for (int ks = 0; ks < 2; ++ks) {
    int ql = (w << 4) + l16;
    uint4 tmp = {0u, 0u, 0u, 0u};
    if (q0 + ql < len)
      tmp = *(const uint4*)(qb + (size_t)(s0 + q0 + ql) * 512 + (h << 6) + (((ks << 2) + quad) << 3));
    afq[ks] = __builtin_bit_cast(bf16x8, tmp);
  }

  // ones B-operand for the l-row-sum MFMA (f16 1.0 = 0x3C00)
  const uint4 onesu = {0x3C003C00u, 0x3C003C00u, 0x3C003C00u, 0x3C003C00u};
  const f16x8 vone = __builtin_bit_cast(f16x8, onesu);

  f32x4 Ol = (f32x4){0.f, 0.f, 0.f, 0.f};   // l[q] in every column
  f32x4 O[4];
#pragma unroll
  for (int dt = 0; dt < 4; ++dt) O[dt] = (f32x4){0.f, 0.f, 0.f, 0.f};

  const int delta = s0 & 7;               // alignment shift of kv window
  const int srl = lane >> 3, sc = lane & 7;
  int vcl = ((len - 8 + delta) & ~7) - delta;   // safe aligned start, +8 <= len
  if (vcl < -delta) vcl = -delta;

  // per-lane incremental staging offsets (u16 units), window at kv0=-delta
  const int rb0 = (w << 4), rb1 = rb0 + 8;
  const int r0 = rb0 + srl, r1 = rb1 + srl;
  const int ca0 = sc ^ (r0 & 7), ca1 = sc ^ (r1 & 7);
  const int t0 = s0 - delta;
  int tk = t0 + r0;
  u32 kOffA = ((tk >> 6) << 12) + ((tk & 63) << 6) + (ca0 << 3);
  tk = t0 + r1;
  u32 kOffB = ((tk >> 6) << 12) + ((tk & 63) << 6) + (ca1 << 3);
  int tv = t0 + (ca0 << 3);
  u32 vOffA = ((tv >> 6) << 12) + (r0 << 6) + (tv & 63);
  tv = t0 + (ca1 << 3);
  u32 vOffB = ((tv >> 6) << 12) + (r1 << 6) + (tv & 63);

  auto stage = [&](int kv0, u16* bk, u16* bvs) {
    if (kv0 + 64 <= len) {                 // interior: pure pointer advance
      gl_lds16(kh + kOffA, bk + (rb0 << 6));
      gl_lds16(kh + kOffB, bk + (rb1 << 6));
      gl_lds16(vh + vOffA, bvs + (rb0 << 6));
      gl_lds16(vh + vOffB, bvs + (rb1 << 6));
    } else {                               // final window: clamped addressing
      int tr = kv0 + r0; tr = tr < len - 1 ? tr : len - 1; int tc = s0 + tr;
      gl_lds16(kh + ((tc >> 6) << 12) + ((tc & 63) << 6) + (ca0 << 3), bk + (rb0 << 6));
      tr = kv0 + r1; tr = tr < len - 1 ? tr : len - 1; tc = s0 + tr;
      gl_lds16(kh + ((tc >> 6) << 12) + ((tc & 63) << 6) + (ca1 << 3), bk + (rb1 << 6));
      int st = kv0 + (ca0 << 3); st = st < len ? st : vcl; tc = s0 + st;
      gl_lds16(vh + ((tc >> 6) << 12) + (r0 << 6) + (tc & 63), bvs + (rb0 << 6));
      st = kv0 + (ca1 << 3); st = st < len ? st : vcl; tc = s0 + st;
      gl_lds16(vh + ((tc >> 6) << 12) + (r1 << 6) + (tc & 63), bvs + (rb1 << 6));
    }
    kOffA += 4096; kOffB += 4096; vOffA += 4096; vOffB += 4096;
  };

  const int nIt = (len + delta + 63) >> 6;

  auto body = [&](int kv0, int i, const u16* Kc, const u16* Vc, u16* Kn, u16* Vn) {
    __syncthreads();                        // cur buffers landed; prev reads done
    if (i + 1 < nIt) stage(kv0 + 64, Kn, Vn);

    // S^T = K Q^T (pre-scaled, log2 domain): lane holds S[key][q=l16]
    f32x4 s[4];
#pragma unroll
    for (int nt = 0; nt < 4; ++nt) s[nt] = (f32x4){0.f, 0.f, 0.f, 0.f};
    __builtin_amdgcn_s_setprio(1);
#pragma unroll
    for (int ks = 0; ks < 2; ++ks) {
#pragma unroll
      for (int nt = 0; nt < 4; ++nt) {
        int kr = (nt << 4) + l16;
        bf16x8 bk = *(const bf16x8*)(Kc + (kr << 6) + ((((ks << 2) + quad) ^ (kr & 7)) << 3));
        s[nt] = __builtin_amdgcn_mfma_f32_16x16x32_bf16(bk, afq[ks], s[nt], 0, 0, 0);
      }
    }
    __builtin_amdgcn_s_setprio(0);
    // key mask only on edge windows (wave-uniform branch); key = quad*4+r now
    if ((kv0 < 0) | (kv0 + 64 > len)) {
#pragma unroll
      for (int nt = 0; nt < 4; ++nt)
#pragma unroll
        for (int r = 0; r < 4; ++r) {
          int ki = kv0 + (nt << 4) + (quad << 2) + r;
          s[nt][r] += ((unsigned)ki < (unsigned)len) ? 0.f : -1e30f;
        }
    }
    // exp2 (l-sum now rides the MFMA pipe via the ones-operand)
#pragma unroll
    for (int nt = 0; nt < 4; ++nt)
#pragma unroll
      for (int r = 0; r < 4; ++r) s[nt][r] = __builtin_amdgcn_exp2f(s[nt][r]);

    // P -> f16 pairs in-register
    u32 pr[8];
#pragma unroll
    for (int nt = 0; nt < 4; ++nt) {
      pr[nt * 2 + 0] = __builtin_bit_cast(u32, __builtin_amdgcn_cvt_pkrtz(s[nt][0], s[nt][1]));
      pr[nt * 2 + 1] = __builtin_bit_cast(u32, __builtin_amdgcn_cvt_pkrtz(s[nt][2], s[nt][3]));
    }
    // PV: assemble A-frags with keys in NATURAL 8*quad+j order:
    // apv[c]@q = pr[2(q>>1)+(c&1)] @ quad 2(q&1)+(c>>1)
    //          = swap32+swap16 of (A,C) and (B,D). V read stays chunk=quad.
#pragma unroll
    for (int ks = 0; ks < 2; ++ks) {
      u32 A = pr[4 * ks + 0], B = pr[4 * ks + 1];
      u32 C = pr[4 * ks + 2], D = pr[4 * ks + 3];
      asm("v_permlane32_swap_b32 %0, %1" : "+v"(A), "+v"(C));
      asm("v_permlane16_swap_b32 %0, %1" : "+v"(A), "+v"(C));
      asm("v_permlane32_swap_b32 %0, %1" : "+v"(B), "+v"(D));
      asm("v_permlane16_swap_b32 %0, %1" : "+v"(B), "+v"(D));
      uint4 apv = {A, B, C, D};
      f16x8 ap = __builtin_bit_cast(f16x8, apv);
      __builtin_amdgcn_s_setprio(1);
#pragma unroll
      for (int dt = 0; dt < 4; ++dt) {
        int vr = (dt << 4) + l16;
        f16x8 bv = *(const f16x8*)(Vc + (vr << 6) + ((((ks << 2) + quad) ^ (vr & 7)) << 3));
        O[dt] = __builtin_amdgcn_mfma_f32_16x16x32_f16(ap, bv, O[dt], 0, 0, 0);
      }
      // l-row-sum on the matrix pipe: D[q][c] = sum_k P[q][k] for every c
      Ol = __builtin_amdgcn_mfma_f32_16x16x32_f16(ap, vone, Ol, 0, 0, 0);
      __builtin_amdgcn_s_setprio(0);
    }
  };

  stage(-delta, Ks[0], Vs[0]);
  {
    int kv0 = -delta, i = 0;
    while (i < nIt) {
      body(kv0, i, Ks[0], Vs[0], Ks[1], Vs[1]);
      ++i; kv0 += 64;
      if (i >= nIt) break;
      body(kv0, i, Ks[1], Vs[1], Ks[0], Vs[0]);
      ++i; kv0 += 64;
    }
  }

  // normalize + store: Ol[r] holds l for q = quad*4+r (all columns equal)
  {
    f32x4 inv;
#pragma unroll
    for (int r = 0; r < 4; ++r) inv[r] = 1.f / Ol[r];
#pragma unroll
    for (int dt = 0; dt < 4; ++dt)
#pragma unroll
      for (int r = 0; r < 4; ++r) {
        int ql = (w << 4) + (quad << 2) + r;
        if (q0 + ql < len)
          ctx[(size_t)(s0 + q0 + ql) * 512 + (h << 6) + (dt << 4) + l16] = (u16)f2bf_u(O[dt][r] * inv[r]);
      }
  }
}

// ---------------------------------------------------------------------------
extern "C" void kernel_launch(void* const* d_in, const int* in_sizes, int n_in,
                              void* d_out, int out_size, void* d_ws, size_t ws_size,
                              hipStream_t stream) {
  const float* x = (const float*)d_in[0];
  const int* batch = (const int*)d_in[1];   // harness passes integers as int32
  const float* ipw = (const float*)d_in[2];
  const float* ipb = (const float*)d_in[3];
  const float* opw = (const float*)d_in[4];
  const float* opb = (const float*)d_in[5];
  const float* lw = (const float*)d_in[6];
  const float* lb = (const float*)d_in[7];
  float* out = (float*)d_out;
  char* ws = (char*)d_ws;

  u16* xb   = (u16*)(ws + 0);              // 16 MB (x bf16)
  u16* ctxb = (u16*)(ws + 0);              // aliases xb (disjoint liveness)
  u16* qb   = (u16*)(ws + 16777216);       // 16 MB: [T][512] q (pre-scaled)
  u16* kpk  = (u16*)(ws + 33554432);       // 16 MB: packed K tiles (bf16)
  u16* vpk  = (u16*)(ws + 50331648);       // 16 MB: packed V tiles (f16)
  u16* ipwb = (u16*)(ws + 67108864);       // 1.5 MB
  u16* wcb  = (u16*)(ws + 68681728);       // 0.5 MB
  float* bc = (float*)(ws + 69206016);     // 2 KB
  float* bqk= (float*)(ws + 69208064);     // 4 KB
  int* seg  = (int*)(ws + 69212160);       // 4 KB

  cast_kernel<<<1120, 256, 0, stream>>>(x, ipw, xb, ipwb);
  wc_seg_kernel<<<273, 256, 0, stream>>>(batch, ipb, bqk, seg, lw, opw, opb, lb,
                                         wcb, bc);
  gemm_qkv<<<1536, 256, 0, stream>>>(xb, ipwb, qb, kpk, vpk, bqk, ipb);
  attn_kernel<<<dim3(MAXT, 8), 256, 0, stream>>>(qb, kpk, vpk, ctxb, seg);
  gemm_out<<<512, 256, 0, stream>>>(ctxb, wcb, out, bc);
  (void)in_sizes; (void)n_in; (void)out_size; (void)ws_size;
}

// Round 15
// 240.677 us; speedup vs baseline: 1.0333x; 1.0004x over previous
//
#include <hip/hip_runtime.h>
#include <stdint.h>
#include <stddef.h>

typedef unsigned short u16;
typedef unsigned int u32;
typedef __bf16 bf16x8 __attribute__((ext_vector_type(8)));
typedef _Float16 f16x8 __attribute__((ext_vector_type(8)));
typedef float f32x4 __attribute__((ext_vector_type(4)));

#define TT 16384
#define NG 16
#define MAXT 272   // sum_g ceil(len_g/64) <= 256+16 = 272; 272 = 8*34
#define SCL 0.18033688011112042f   // log2(e)/sqrt(64)

static __device__ __forceinline__ unsigned f2bf_u(float f) {
  unsigned u = __float_as_uint(f);
  return (u + 0x7fffu + ((u >> 16) & 1u)) >> 16;   // RNE fp32->bf16
}

// async global->LDS, 16B per lane; LDS dst is wave-uniform base + lane*16
static __device__ __forceinline__ void gl_lds16(const u16* g, u16* l) {
  __builtin_amdgcn_global_load_lds(
      (const __attribute__((address_space(1))) u32*)g,
      (__attribute__((address_space(3))) u32*)l, 16, 0, 0);
}

// DPP cross-lane within 16-lane row (VALU pipe, no DS traffic)
template <int CTRL>
static __device__ __forceinline__ float dppf(float x) {
  return __int_as_float(__builtin_amdgcn_mov_dpp(__float_as_int(x), CTRL, 0xF, 0xF, true));
}
// xor1=0xB1, xor2=0x4E, ror4=0x124, ror8=0x128, half_mirror=0x141

// ---------------------------------------------------------------------------
// CONSOLIDATED BEST (round 15): every kernel at its best-verified form.
//  - cast/wc_seg: round-9 forms (round-13's NT-load + unroll-8 both negative)
//  - gemm kernels: round-9 forms (XCD swizzle on GEMMs measured neutral r3)
//  - attn: v13 (round-9/13 verified 64.0-64.2us; v14 mt=2 failed correctness,
//    v15 Ol-on-MFMA was +2.3us w/ scratch traffic -> both abandoned)
// Ladder: 323.5 (session start) -> 240.8 best; attn 133.6 -> 64.0.
// ---------------------------------------------------------------------------
#define NXF4 2097152   // 16384*512/4
#define NWQ4 65536     // 512*512/4 (Wq rows of in_proj_w)

__global__ __launch_bounds__(256) void cast_kernel(
    const float* __restrict__ x, const float* __restrict__ ipw,
    u16* __restrict__ xb, u16* __restrict__ ipwb) {
  const int base = blockIdx.x * 2048 + threadIdx.x;
#pragma unroll
  for (int u = 0; u < 8; ++u) {
    int j = base + u * 256;
    float4 f;
    if (j < NXF4) f = ((const float4*)x)[j];
    else          f = ((const float4*)ipw)[j - NXF4];
    if (j >= NXF4 && j < NXF4 + NWQ4) { f.x *= SCL; f.y *= SCL; f.z *= SCL; f.w *= SCL; }
    uint2 o;
    o.x = f2bf_u(f.x) | (f2bf_u(f.y) << 16);
    o.y = f2bf_u(f.z) | (f2bf_u(f.w) << 16);
    if (j < NXF4) ((uint2*)xb)[j] = o;
    else          ((uint2*)ipwb)[j - NXF4] = o;
  }
}

// ---------------------------------------------------------------------------
// wc_seg_kernel: 273 blocks, all co-resident (zero dispatch tail).
//  blocks 0..255  : Wc = Wl*Wo, K-split x4; sWlT transposed+padded staging.
//  blocks 256..271: bc = Wl*bo + bl, 8-lane DPP reduce.
//  block 272      : seg worklist + bqk bias scale.
// ---------------------------------------------------------------------------
__global__ __launch_bounds__(256) void wc_seg_kernel(
    const int* __restrict__ batch, const float* __restrict__ ipb,
    float* __restrict__ bqk, int* __restrict__ seg,
    const float* __restrict__ Wl, const float* __restrict__ Wo,
    const float* __restrict__ bo, const float* __restrict__ bl,
    u16* __restrict__ Wc, float* __restrict__ bc) {
  const int tid = threadIdx.x;
  const int bxx = blockIdx.x;
  __shared__ float sWlT[512 * 20];   // [k][r], padded 16->20 for b128 align
  __shared__ float red2[4096];       // [ks][16][64]
  __shared__ int scnt[NG];
  if (bxx < 256) {                   // ---- wc part ----
    const int r0 = (bxx >> 3) << 4;  // 32 row-groups of 16
    const int c0 = (bxx & 7) << 6;   // 8 col-groups of 64
    for (int i = tid; i < 16 * 512; i += 256) {
      int r = i >> 9, k = i & 511;
      sWlT[k * 20 + r] = Wl[(r0 + r) * 512 + k];
    }
    __syncthreads();
    const int c = c0 + (tid & 63), ks = tid >> 6;
    float a[16];
#pragma unroll
    for (int r = 0; r < 16; ++r) a[r] = 0.f;
    const int kbeg = ks << 7;
#pragma unroll 4
    for (int kk = 0; kk < 128; ++kk) {
      int k = kbeg + kk;
      float w = Wo[k * 512 + c];
      const f32x4* sp = (const f32x4*)(sWlT + k * 20);
#pragma unroll
      for (int rq = 0; rq < 4; ++rq) {
        f32x4 v = sp[rq];
        a[rq * 4 + 0] += v[0] * w; a[rq * 4 + 1] += v[1] * w;
        a[rq * 4 + 2] += v[2] * w; a[rq * 4 + 3] += v[3] * w;
      }
    }
#pragma unroll
    for (int r = 0; r < 16; ++r) red2[(ks << 10) + (r << 6) + (tid & 63)] = a[r];
    __syncthreads();
#pragma unroll
    for (int q = 0; q < 4; ++q) {
      int oi = (q << 8) + tid;       // 0..1023 -> (r, cc)
      int r = oi >> 6, cc = oi & 63;
      float v = (red2[(r << 6) + cc] + red2[1024 + (r << 6) + cc]) +
                (red2[2048 + (r << 6) + cc] + red2[3072 + (r << 6) + cc]);
      Wc[(size_t)(r0 + r) * 512 + c0 + cc] = (u16)f2bf_u(v);
    }
    return;
  }
  if (bxx < 272) {                   // ---- bc part: 32 rows/block ----
    const int row = ((bxx - 256) << 5) + (tid >> 3), s = tid & 7;
    float acc = 0.f;
#pragma unroll 8
    for (int j = 0; j < 64; ++j)
      acc += Wl[(size_t)row * 512 + (j << 3) + s] * bo[(j << 3) + s];
    acc += dppf<0xB1>(acc);          // xor1
    acc += dppf<0x4E>(acc);          // xor2
    acc += dppf<0x141>(acc);         // row_half_mirror
    if (s == 0) bc[row] = acc + bl[row];
    return;
  }
  // ---- seg part (bxx == 272) ----
  if (tid < NG) scnt[tid] = 0;
  __syncthreads();
  for (int i = tid; i < TT; i += 256) atomicAdd(&scnt[batch[i] & (NG - 1)], 1);
  for (int i = tid; i < 1024; i += 256) bqk[i] = ipb[i] * (i < 512 ? SCL : 1.f);
  __syncthreads();
  if (tid == 0) {
    int off = 0, nt = 0;
    for (int g = 0; g < NG; ++g) { seg[1 + g] = off; off += scnt[g]; }
    seg[1 + NG] = off;
    for (int g = 0; g < NG; ++g)
      for (int q0 = 0; q0 < scnt[g]; q0 += 64) { seg[32 + nt] = g; seg[320 + nt] = q0; ++nt; }
    seg[0] = nt;
  }
}

// ---------------------------------------------------------------------------
// gemm_core: C = A[M,K] * Bt[N,K]^T + bias   (bf16 MFMA 16x16x32)
// 128x128 tile, BK=64, 4 waves, 4x4 acc frags; swizzled LDS; gl_lds16 staging.
// EPI 0: f32 row-major, bias[col]          (final output)
// EPI 1: col<512 -> q row-major bf16; col>=512 -> K packed tiles (bf16)
//        kpk[h][t/64][t&63][d]
// EPI 2: V packed tiles in F16, bias[row]
//        vpk[h][t/64][d][t&63]
// ---------------------------------------------------------------------------
template <int EPI>
static __device__ __forceinline__ void gemm_core(
    u16* As, u16* Bs, int bidx,
    const u16* __restrict__ A, const u16* __restrict__ Bt, void* __restrict__ C,
    void* __restrict__ C2, const float* __restrict__ bias, int M, int N, int K) {
  const int nn = N >> 7;
  const int bm = bidx / nn, bn = bidx % nn;
  const int tid = threadIdx.x;
  const int w = tid >> 6, lane = tid & 63;
  const int quad = lane >> 4, l16 = lane & 15;
  const int wm = w >> 1, wn = w & 1;
  f32x4 acc[4][4];
#pragma unroll
  for (int mi = 0; mi < 4; ++mi)
#pragma unroll
    for (int ni = 0; ni < 4; ++ni) acc[mi][ni] = (f32x4){0.f, 0.f, 0.f, 0.f};
  const int sr = lane >> 3, scn = lane & 7;
  const int rowA0 = bm << 7, rowB0 = bn << 7;
  for (int kt = 0; kt < K; kt += 64) {
#pragma unroll
    for (int u = 0; u < 4; ++u) {
      int rbase = (w << 5) + (u << 3);
      int ml = rbase + sr;
      int ca = scn ^ (ml & 7);
      gl_lds16(A  + (size_t)(rowA0 + ml) * K + kt + ca * 8, As + (rbase << 6));
      gl_lds16(Bt + (size_t)(rowB0 + ml) * K + kt + ca * 8, Bs + (rbase << 6));
    }
    __syncthreads();
#pragma unroll
    for (int ks = 0; ks < 2; ++ks) {
      bf16x8 af[4], bfv[4];
#pragma unroll
      for (int mi = 0; mi < 4; ++mi) {
        int r = (wm << 6) + (mi << 4) + l16;
        af[mi] = *(const bf16x8*)(As + (r << 6) + ((((ks << 2) + quad) ^ (r & 7)) << 3));
      }
#pragma unroll
      for (int ni = 0; ni < 4; ++ni) {
        int r = (wn << 6) + (ni << 4) + l16;
        bfv[ni] = *(const bf16x8*)(Bs + (r << 6) + ((((ks << 2) + quad) ^ (r & 7)) << 3));
      }
#pragma unroll
      for (int mi = 0; mi < 4; ++mi)
#pragma unroll
        for (int ni = 0; ni < 4; ++ni)
          acc[mi][ni] = __builtin_amdgcn_mfma_f32_16x16x32_bf16(af[mi], bfv[ni], acc[mi][ni], 0, 0, 0);
    }
    __syncthreads();
  }
#pragma unroll
  for (int mi = 0; mi < 4; ++mi) {
#pragma unroll
    for (int ni = 0; ni < 4; ++ni) {
      int row = rowA0 + (wm << 6) + (mi << 4) + (quad << 2);
      int col = rowB0 + (wn << 6) + (ni << 4) + l16;
      float bvc = (EPI == 2) ? 0.f : bias[col];
#pragma unroll
      for (int r = 0; r < 4; ++r) {
        float v = acc[mi][ni][r] + ((EPI == 2) ? bias[row + r] : bvc);
        if (EPI == 0) {
          ((float*)C)[(size_t)(row + r) * N + col] = v;
        } else if (EPI == 1) {
          if (col < 512) {
            ((u16*)C)[(size_t)(row + r) * 512 + col] = (u16)f2bf_u(v);
          } else {
            int f = col - 512, hh = f >> 6, d = f & 63, t = row + r;
            ((u16*)C2)[(size_t)hh * (TT * 64) + ((t >> 6) << 12) + ((t & 63) << 6) + d] = (u16)f2bf_u(v);
          }
        } else {
          int f = row + r, hh = f >> 6, d = f & 63, t = col;
          ((u16*)C)[(size_t)hh * (TT * 64) + ((t >> 6) << 12) + (d << 6) + (t & 63)] =
              __builtin_bit_cast(unsigned short, (_Float16)v);
        }
      }
    }
  }
}

// fused projection GEMMs: blocks 0..1023 -> QK (EPI1); 1024..1535 -> V (EPI2)
__global__ __launch_bounds__(256) void gemm_qkv(
    const u16* __restrict__ xb, const u16* __restrict__ ipwb,
    u16* __restrict__ qb, u16* __restrict__ kpk, u16* __restrict__ vpk,
    const float* __restrict__ bqk, const float* __restrict__ ipb) {
  __shared__ __align__(16) u16 As[128 * 64];
  __shared__ __align__(16) u16 Bs[128 * 64];
  if (blockIdx.x < 1024)
    gemm_core<1>(As, Bs, blockIdx.x, xb, ipwb, qb, kpk, bqk, TT, 1024, 512);
  else
    gemm_core<2>(As, Bs, blockIdx.x - 1024, ipwb + 1024 * 512, xb, vpk, nullptr,
                 ipb + 1024, 512, TT, 512);
}

__global__ __launch_bounds__(256) void gemm_out(
    const u16* __restrict__ ctxb, const u16* __restrict__ wcb,
    float* __restrict__ out, const float* __restrict__ bc) {
  __shared__ __align__(16) u16 As[128 * 64];
  __shared__ __align__(16) u16 Bs[128 * 64];
  gemm_core<0>(As, Bs, blockIdx.x, ctxb, wcb, out, nullptr, bc, TT, 512, 512);
}

// ---------------------------------------------------------------------------
// attn v13 (VERIFIED twice: 64.2us r9, 64.0us r13; absmax 6.1e-5):
// in-register softmax via swapped QK^T (lane holds P[key][q=l16]) +
// permlane A-frag assembly in natural key order (V read conflict-free) +
// XCD tile swizzle (FETCH 146->32MB) + (256,5), LDS 32KB, VGPR 44.
// Abandoned variants: mt=2 (v14, correctness), l-sum-on-MFMA (v15, +2.3us
// + scratch traffic — attn is dependency-bound, not VALU-throughput-bound).
// ---------------------------------------------------------------------------
__global__ __launch_bounds__(256, 5) void attn_kernel(
    const u16* __restrict__ qb, const u16* __restrict__ kpk,
    const u16* __restrict__ vpk, u16* __restrict__ ctx, const int* __restrict__ seg) {
  const int bxr = blockIdx.x;
  const int bx = ((bxr & 7) * 34) + (bxr >> 3);   // XCD-contiguous tiles
  if (bx >= seg[0]) return;
  const int h = blockIdx.y;
  const int g = seg[32 + bx], q0 = seg[320 + bx];
  const int s0 = seg[1 + g], len = seg[2 + g] - s0;
  const int tid = threadIdx.x, w = tid >> 6, lane = tid & 63;
  const int quad = lane >> 4, l16 = lane & 15;

  __shared__ __align__(16) u16 Ks[2][4096];
  __shared__ __align__(16) u16 Vs[2][4096];

  const u16* kh = kpk + (size_t)h * (TT * 64);
  const u16* vh = vpk + (size_t)h * (TT * 64);

  // Q fragments, 16 rows/wave, zero beyond len (used as B-operand now)
  bf16x8 afq[2];
#pragma unroll
  for (int ks = 0; ks < 2; ++ks) {
    int ql = (w << 4) + l16;
    uint4 tmp = {0u, 0u, 0u, 0u};
    if (q0 + ql < len)
      tmp = *(const uint4*)(qb + (size_t)(s0 + q0 + ql) * 512 + (h << 6) + (((ks << 2) + quad) << 3));
    afq[ks] = __builtin_bit_cast(bf16x8, tmp);
  }

  float lacc = 0.f;
  f32x4 O[4];
#pragma unroll
  for (int dt = 0; dt < 4; ++dt) O[dt] = (f32x4){0.f, 0.f, 0.f, 0.f};

  const int delta = s0 & 7;               // alignment shift of kv window
  const int srl = lane >> 3, sc = lane & 7;
  int vcl = ((len - 8 + delta) & ~7) - delta;   // safe aligned start, +8 <= len
  if (vcl < -delta) vcl = -delta;

  // per-lane incremental staging offsets (u16 units), window at kv0=-delta
  const int rb0 = (w << 4), rb1 = rb0 + 8;
  const int r0 = rb0 + srl, r1 = rb1 + srl;
  const int ca0 = sc ^ (r0 & 7), ca1 = sc ^ (r1 & 7);
  const int t0 = s0 - delta;
  int tk = t0 + r0;
  u32 kOffA = ((tk >> 6) << 12) + ((tk & 63) << 6) + (ca0 << 3);
  tk = t0 + r1;
  u32 kOffB = ((tk >> 6) << 12) + ((tk & 63) << 6) + (ca1 << 3);
  int tv = t0 + (ca0 << 3);
  u32 vOffA = ((tv >> 6) << 12) + (r0 << 6) + (tv & 63);
  tv = t0 + (ca1 << 3);
  u32 vOffB = ((tv >> 6) << 12) + (r1 << 6) + (tv & 63);

  auto stage = [&](int kv0, u16* bk, u16* bvs) {
    if (kv0 + 64 <= len) {                 // interior: pure pointer advance
      gl_lds16(kh + kOffA, bk + (rb0 << 6));
      gl_lds16(kh + kOffB, bk + (rb1 << 6));
      gl_lds16(vh + vOffA, bvs + (rb0 << 6));
      gl_lds16(vh + vOffB, bvs + (rb1 << 6));
    } else {                               // final window: clamped addressing
      int tr = kv0 + r0; tr = tr < len - 1 ? tr : len - 1; int tc = s0 + tr;
      gl_lds16(kh + ((tc >> 6) << 12) + ((tc & 63) << 6) + (ca0 << 3), bk + (rb0 << 6));
      tr = kv0 + r1; tr = tr < len - 1 ? tr : len - 1; tc = s0 + tr;
      gl_lds16(kh + ((tc >> 6) << 12) + ((tc & 63) << 6) + (ca1 << 3), bk + (rb1 << 6));
      int st = kv0 + (ca0 << 3); st = st < len ? st : vcl; tc = s0 + st;
      gl_lds16(vh + ((tc >> 6) << 12) + (r0 << 6) + (tc & 63), bvs + (rb0 << 6));
      st = kv0 + (ca1 << 3); st = st < len ? st : vcl; tc = s0 + st;
      gl_lds16(vh + ((tc >> 6) << 12) + (r1 << 6) + (tc & 63), bvs + (rb1 << 6));
    }
    kOffA += 4096; kOffB += 4096; vOffA += 4096; vOffB += 4096;
  };

  const int nIt = (len + delta + 63) >> 6;

  auto body = [&](int kv0, int i, const u16* Kc, const u16* Vc, u16* Kn, u16* Vn) {
    __syncthreads();                        // cur buffers landed; prev reads done
    if (i + 1 < nIt) stage(kv0 + 64, Kn, Vn);

    // S^T = K Q^T (pre-scaled, log2 domain): lane holds S[key][q=l16]
    f32x4 s[4];
#pragma unroll
    for (int nt = 0; nt < 4; ++nt) s[nt] = (f32x4){0.f, 0.f, 0.f, 0.f};
    __builtin_amdgcn_s_setprio(1);
#pragma unroll
    for (int ks = 0; ks < 2; ++ks) {
#pragma unroll
      for (int nt = 0; nt < 4; ++nt) {
        int kr = (nt << 4) + l16;
        bf16x8 bk = *(const bf16x8*)(Kc + (kr << 6) + ((((ks << 2) + quad) ^ (kr & 7)) << 3));
        s[nt] = __builtin_amdgcn_mfma_f32_16x16x32_bf16(bk, afq[ks], s[nt], 0, 0, 0);
      }
    }
    __builtin_amdgcn_s_setprio(0);
    // key mask only on edge windows (wave-uniform branch); key = quad*4+r now
    if ((kv0 < 0) | (kv0 + 64 > len)) {
#pragma unroll
      for (int nt = 0; nt < 4; ++nt)
#pragma unroll
        for (int r = 0; r < 4; ++r) {
          int ki = kv0 + (nt << 4) + (quad << 2) + r;
          s[nt][r] += ((unsigned)ki < (unsigned)len) ? 0.f : -1e30f;
        }
    }
    // exp2 + scalar l partial (all 16 values belong to q=l16)
#pragma unroll
    for (int nt = 0; nt < 4; ++nt)
#pragma unroll
      for (int r = 0; r < 4; ++r) s[nt][r] = __builtin_amdgcn_exp2f(s[nt][r]);
#pragma unroll
    for (int nt = 0; nt < 4; ++nt)
      lacc += (s[nt][0] + s[nt][1]) + (s[nt][2] + s[nt][3]);

    // P -> f16 pairs in-register
    u32 pr[8];
#pragma unroll
    for (int nt = 0; nt < 4; ++nt) {
      pr[nt * 2 + 0] = __builtin_bit_cast(u32, __builtin_amdgcn_cvt_pkrtz(s[nt][0], s[nt][1]));
      pr[nt * 2 + 1] = __builtin_bit_cast(u32, __builtin_amdgcn_cvt_pkrtz(s[nt][2], s[nt][3]));
    }
    // PV: assemble A-frags with keys in NATURAL 8*quad+j order:
    // apv[c]@q = pr[2(q>>1)+(c&1)] @ quad 2(q&1)+(c>>1)
    //          = swap32+swap16 of (A,C) and (B,D). V read stays chunk=quad.
#pragma unroll
    for (int ks = 0; ks < 2; ++ks) {
      u32 A = pr[4 * ks + 0], B = pr[4 * ks + 1];
      u32 C = pr[4 * ks + 2], D = pr[4 * ks + 3];
      asm("v_permlane32_swap_b32 %0, %1" : "+v"(A), "+v"(C));
      asm("v_permlane16_swap_b32 %0, %1" : "+v"(A), "+v"(C));
      asm("v_permlane32_swap_b32 %0, %1" : "+v"(B), "+v"(D));
      asm("v_permlane16_swap_b32 %0, %1" : "+v"(B), "+v"(D));
      uint4 apv = {A, B, C, D};
      f16x8 ap = __builtin_bit_cast(f16x8, apv);
      __builtin_amdgcn_s_setprio(1);
#pragma unroll
      for (int dt = 0; dt < 4; ++dt) {
        int vr = (dt << 4) + l16;
        f16x8 bv = *(const f16x8*)(Vc + (vr << 6) + ((((ks << 2) + quad) ^ (vr & 7)) << 3));
        O[dt] = __builtin_amdgcn_mfma_f32_16x16x32_f16(ap, bv, O[dt], 0, 0, 0);
      }
      __builtin_amdgcn_s_setprio(0);
    }
  };

  stage(-delta, Ks[0], Vs[0]);
  {
    int kv0 = -delta, i = 0;
    while (i < nIt) {
      body(kv0, i, Ks[0], Vs[0], Ks[1], Vs[1]);
      ++i; kv0 += 64;
      if (i >= nIt) break;
      body(kv0, i, Ks[1], Vs[1], Ks[0], Vs[0]);
      ++i; kv0 += 64;
    }
  }

  // fold l across the 4 quads (each lane holds partial for q=l16)
  {
    u32 a = __float_as_uint(lacc), b = a;
    asm("v_permlane32_swap_b32 %0, %1" : "+v"(a), "+v"(b));
    float t = __uint_as_float(a) + __uint_as_float(b);
    a = __float_as_uint(t); b = a;
    asm("v_permlane16_swap_b32 %0, %1" : "+v"(a), "+v"(b));
    lacc = __uint_as_float(a) + __uint_as_float(b);
  }
  // inv per (quad, r): O rows are q = quad*4+r; L lives at lane l16=q
  {
    f32x4 inv;
#pragma unroll
    for (int r = 0; r < 4; ++r) {
      float Lr = __int_as_float(
          __builtin_amdgcn_ds_bpermute((((quad << 2) + r) << 2), __float_as_int(lacc)));
      inv[r] = 1.f / Lr;
    }
#pragma unroll
    for (int dt = 0; dt < 4; ++dt)
#pragma unroll
      for (int r = 0; r < 4; ++r) {
        int ql = (w << 4) + (quad << 2) + r;
        if (q0 + ql < len)
          ctx[(size_t)(s0 + q0 + ql) * 512 + (h << 6) + (dt << 4) + l16] = (u16)f2bf_u(O[dt][r] * inv[r]);
      }
  }
}

// ---------------------------------------------------------------------------
extern "C" void kernel_launch(void* const* d_in, const int* in_sizes, int n_in,
                              void* d_out, int out_size, void* d_ws, size_t ws_size,
                              hipStream_t stream) {
  const float* x = (const float*)d_in[0];
  const int* batch = (const int*)d_in[1];   // harness passes integers as int32
  const float* ipw = (const float*)d_in[2];
  const float* ipb = (const float*)d_in[3];
  const float* opw = (const float*)d_in[4];
  const float* opb = (const float*)d_in[5];
  const float* lw = (const float*)d_in[6];
  const float* lb = (const float*)d_in[7];
  float* out = (float*)d_out;
  char* ws = (char*)d_ws;

  u16* xb   = (u16*)(ws + 0);              // 16 MB (x bf16)
  u16* ctxb = (u16*)(ws + 0);              // aliases xb (disjoint liveness)
  u16* qb   = (u16*)(ws + 16777216);       // 16 MB: [T][512] q (pre-scaled)
  u16* kpk  = (u16*)(ws + 33554432);       // 16 MB: packed K tiles (bf16)
  u16* vpk  = (u16*)(ws + 50331648);       // 16 MB: packed V tiles (f16)
  u16* ipwb = (u16*)(ws + 67108864);       // 1.5 MB
  u16* wcb  = (u16*)(ws + 68681728);       // 0.5 MB
  float* bc = (float*)(ws + 69206016);     // 2 KB
  float* bqk= (float*)(ws + 69208064);     // 4 KB
  int* seg  = (int*)(ws + 69212160);       // 4 KB

  cast_kernel<<<1120, 256, 0, stream>>>(x, ipw, xb, ipwb);
  wc_seg_kernel<<<273, 256, 0, stream>>>(batch, ipb, bqk, seg, lw, opw, opb, lb,
                                         wcb, bc);
  gemm_qkv<<<1536, 256, 0, stream>>>(xb, ipwb, qb, kpk, vpk, bqk, ipb);
  attn_kernel<<<dim3(MAXT, 8), 256, 0, stream>>>(qb, kpk, vpk, ctxb, seg);
  gemm_out<<<512, 256, 0, stream>>>(ctxb, wcb, out, bc);
  (void)in_sizes; (void)n_in; (void)out_size; (void)ws_size;
}